// Round 16
// baseline (114.877 us; speedup 1.0000x reference)
//
#include <hip/hip_runtime.h>
#include <hip/hip_bf16.h>
#include <stdint.h>

constexpr int K   = 49;     // 7x7 kernel flattened
constexpr int C   = 32;     // out channels
constexpr int WPT = 16;     // windows per wave-tile (MFMA N dim)
constexpr int NTW = 8;      // tiles per wave (amortize weight/bias setup)
constexpr int BLK = 256;    // 4 independent waves
constexpr int WPB = 4 * WPT * NTW;   // 512 windows per block

typedef short bf16x8 __attribute__((ext_vector_type(8)));
typedef float f32x4  __attribute__((ext_vector_type(4)));
typedef float v4 __attribute__((ext_vector_type(4), aligned(4)));  // 4B-aligned ok

#define GPTR(p) ((const __attribute__((address_space(1))) uint32_t*)(p))
#define LPTR(p) ((__attribute__((address_space(3))) uint32_t*)(p))

static __device__ __forceinline__ short f2bf(float f) {
    __hip_bfloat16 h = __float2bfloat16(f);      // RNE
    return __builtin_bit_cast(short, h);
}

// Zero-LDS MFMA streaming kernel. Swapped operands: A = weights (M=channel,
// hoisted to 16 VGPR once), B = x windows loaded global->reg per micro-tile.
// Per tile: 4 dwordx4 + cvt + 4 MFMA + 8 stores (4x64B runs each). No LDS,
// no barriers, no block-wide drains -> every wave is an independent
// fine-grained pipeline; ~65 VGPR keeps high occupancy without spill.
__global__ __launch_bounds__(BLK) void conv2d_dmfma(
    const float* __restrict__ enc_x,
    const float* __restrict__ weight,   // [C*K]
    const float* __restrict__ bias,     // [C]
    float* __restrict__ out,            // [C * windows_nb]
    int windows_nb)
{
    const int t    = threadIdx.x;
    const int lane = t & 63;
    const int lo   = lane & 15, hi = lane >> 4;
    const int wuni = __builtin_amdgcn_readfirstlane(t >> 6);

    const size_t w0 = (size_t)blockIdx.x * WPB + (size_t)wuni * (WPT * NTW);

    // ---- A-fragments (weights): lane holds channels {lo, lo+16}; k>=49 -> 0 ----
    bf16x8 wa[2][2];                      // [m][ks]
#pragma unroll
    for (int m = 0; m < 2; ++m)
#pragma unroll
        for (int ks = 0; ks < 2; ++ks) {
            short tmp[8];
#pragma unroll
            for (int e = 0; e < 8; ++e) {
                const int kk = hi * 8 + ks * 32 + e;
                tmp[e] = f2bf(kk < K ? weight[(m * 16 + lo) * K + kk] : 0.f);
            }
            wa[m][ks] = *reinterpret_cast<bf16x8*>(tmp);
        }

    // ---- bias fragment: D element (m,r) is channel m*16 + hi*4 + r ----
    float bv[2][4];
#pragma unroll
    for (int m = 0; m < 2; ++m)
#pragma unroll
        for (int r = 0; r < 4; ++r)
            bv[m][r] = bias[m * 16 + hi * 4 + r];

    const char* __restrict__ xb = reinterpret_cast<const char*>(enc_x);

#pragma unroll
    for (int j = 0; j < NTW; ++j) {
        // B-fragment: lane's window = w0 + j*16 + lo, k = hi*8 + ks*32 + e.
        // Row byte offsets fit u32 (max 205MB). ks=0 reads bytes 0..127 of the
        // row (always in-bounds); ks=1 valid k are 32..48 only:
        //   hi<2 : bytes 128..191 (in-bounds), hi==2: k=48 single dword at 192,
        //   hi==3: all k>=56 -> zeros. No address ever exceeds the buffer.
        const uint32_t off = (uint32_t)(w0 + (size_t)j * WPT + lo) * 196u;

        v4 b0 = *reinterpret_cast<const v4*>(xb + off + hi * 32u);
        v4 b1 = *reinterpret_cast<const v4*>(xb + off + hi * 32u + 16u);
        bf16x8 x0;
        {
            short s[8];
#pragma unroll
            for (int i = 0; i < 4; ++i) { s[i] = f2bf(b0[i]); s[4 + i] = f2bf(b1[i]); }
            x0 = *reinterpret_cast<bf16x8*>(s);
        }

        bf16x8 x1;
        if (hi < 2) {
            v4 b2 = *reinterpret_cast<const v4*>(xb + off + 128u + hi * 32u);
            v4 b3 = *reinterpret_cast<const v4*>(xb + off + 144u + hi * 32u);
            short s[8];
#pragma unroll
            for (int i = 0; i < 4; ++i) { s[i] = f2bf(b2[i]); s[4 + i] = f2bf(b3[i]); }
            x1 = *reinterpret_cast<bf16x8*>(s);
        } else if (hi == 2) {
            const float x48 = *reinterpret_cast<const float*>(xb + off + 192u);
            short s[8] = { f2bf(x48), 0, 0, 0, 0, 0, 0, 0 };
            x1 = *reinterpret_cast<bf16x8*>(s);
        } else {
            x1 = bf16x8{0, 0, 0, 0, 0, 0, 0, 0};
        }

        // ---- 4 MFMAs; bias pre-loaded into the C operand ----
        f32x4 acc[2] = { f32x4{bv[0][0], bv[0][1], bv[0][2], bv[0][3]},
                         f32x4{bv[1][0], bv[1][1], bv[1][2], bv[1][3]} };
#pragma unroll
        for (int m = 0; m < 2; ++m) {
            acc[m] = __builtin_amdgcn_mfma_f32_16x16x32_bf16(wa[m][0], x0, acc[m], 0, 0, 0);
            acc[m] = __builtin_amdgcn_mfma_f32_16x16x32_bf16(wa[m][1], x1, acc[m], 0, 0, 0);
        }

        // ---- stores: D col=lane&15=window, row=(lane>>4)*4+reg=channel ----
        // per instr: 4 channel planes x 16 windows = 4 x 64B coalesced runs
        const size_t wj = w0 + (size_t)j * WPT + lo;
#pragma unroll
        for (int m = 0; m < 2; ++m)
#pragma unroll
            for (int r = 0; r < 4; ++r)
                out[(size_t)(m * 16 + hi * 4 + r) * windows_nb + wj] = acc[m][r];
    }
}

// Known-good fallback (R9 structure, 79.5 us) for unexpected sizes.
__global__ __launch_bounds__(128, 8) void conv2d_split2u(
    const float* __restrict__ enc_x, const float* __restrict__ weight,
    const float* __restrict__ bias, float* __restrict__ out, int windows_nb)
{
    __shared__ __align__(16) float xs[64 * K];
    const int t = threadIdx.x, lane = t & 63, wid = t >> 6;
    const size_t b = blockIdx.x;
    const float* __restrict__ g = enc_x + b * (size_t)(64 * K);
    if (wid == 0) {
#pragma unroll
        for (int r = 0; r < 6; ++r)
            __builtin_amdgcn_global_load_lds(GPTR(g + r * 256 + lane * 4),
                                             LPTR(xs + r * 256 + lane * 4), 16, 0, 0);
    } else {
#pragma unroll
        for (int r = 6; r < 12; ++r)
            __builtin_amdgcn_global_load_lds(GPTR(g + r * 256 + lane * 4),
                                             LPTR(xs + r * 256 + lane * 4), 16, 0, 0);
        __builtin_amdgcn_global_load_lds(GPTR(g + 3072 + lane),
                                         LPTR(xs + 3072 + lane), 4, 0, 0);
    }
    asm volatile("s_waitcnt vmcnt(0)" ::: "memory");
    __builtin_amdgcn_s_barrier();
    const int c0 = __builtin_amdgcn_readfirstlane(wid) * 16;
    const float* __restrict__ wp = weight + c0 * K;
    float acc[16];
#pragma unroll
    for (int cc = 0; cc < 16; ++cc) acc[cc] = bias[c0 + cc];
    float x[25];
#pragma unroll
    for (int k = 0; k < 24; ++k) x[k] = xs[lane * K + k];
#pragma unroll 2
    for (int cc = 0; cc < 16; ++cc) {
        const float* __restrict__ wc = wp + cc * K;
        float a = acc[cc];
#pragma unroll
        for (int k = 0; k < 24; ++k) a = fmaf(x[k], wc[k], a);
        acc[cc] = a;
    }
#pragma unroll
    for (int k = 0; k < 25; ++k) x[k] = xs[lane * K + 24 + k];
#pragma unroll 2
    for (int cc = 0; cc < 16; ++cc) {
        const float* __restrict__ wc = wp + cc * K + 24;
        float a = acc[cc];
#pragma unroll
        for (int k = 0; k < 25; ++k) a = fmaf(x[k], wc[k], a);
        acc[cc] = a;
    }
    const size_t w = b * 64 + lane;
#pragma unroll
    for (int cc = 0; cc < 16; ++cc)
        out[(size_t)(c0 + cc) * windows_nb + w] = acc[cc];
}

extern "C" void kernel_launch(void* const* d_in, const int* in_sizes, int n_in,
                              void* d_out, int out_size, void* d_ws, size_t ws_size,
                              hipStream_t stream) {
    const float* enc_x  = (const float*)d_in[0];
    const float* weight = (const float*)d_in[1];   // [C,7,7] flat
    const float* bias   = (const float*)d_in[2];   // [C]
    float* out = (float*)d_out;

    const int windows_nb = in_sizes[0] / K;        // 1048576 expected

    if ((windows_nb % WPB) == 0) {
        conv2d_dmfma<<<windows_nb / WPB, BLK, 0, stream>>>(enc_x, weight, bias, out, windows_nb);
    } else {
        conv2d_split2u<<<(windows_nb + 63) / 64, 128, 0, stream>>>(enc_x, weight, bias, out, windows_nb);
    }
}

// Round 17
// 87.568 us; speedup vs baseline: 1.3119x; 1.3119x over previous
//
#include <hip/hip_runtime.h>
#include <hip/hip_bf16.h>
#include <stdint.h>

constexpr int K    = 49;             // 7x7 kernel flattened
constexpr int C    = 32;             // out channels
constexpr int WPW  = 32;             // windows per wave-tile
constexpr int RF   = WPW * K;        // 1568 floats per tile
constexpr int REG  = 1600;           // region floats (tail slack)
constexpr int NT   = 8;              // tiles per wave
constexpr int BLK  = 256;            // 4 independent waves
constexpr int WPB  = 4 * WPW * NT;   // 1024 windows per block

typedef short bf16x8 __attribute__((ext_vector_type(8)));
typedef float f32x4  __attribute__((ext_vector_type(4)));

#define GPTR(p) ((const __attribute__((address_space(1))) uint32_t*)(p))
#define LPTR(p) ((__attribute__((address_space(3))) uint32_t*)(p))
#define WAITV(n) asm volatile("s_waitcnt vmcnt(" #n ")" ::: "memory")

static __device__ __forceinline__ short f2bf(float f) {
    __hip_bfloat16 h = __float2bfloat16(f);      // RNE
    return __builtin_bit_cast(short, h);
}

// Persistent decoupled wave-pipelines, depth 2.
// Per-wave VMEM FIFO (S = own stage 7 ops, st = 16 stores), issue order:
//   S0 S1 | j0: W(7) c0 st0 S2 | j1: W(23) c1 st1 S3 | ... | j7: W(16) c7 st7
// wait_j allows younger st_{j-1}(16) + S_{j+1}(7); in-order retirement means
// the waited S_j is never chained behind stores. No barriers after palette.
__global__ __launch_bounds__(BLK) void conv2d_pwave(
    const float* __restrict__ enc_x,
    const float* __restrict__ weight,   // [C*K]
    const float* __restrict__ bias,     // [C]
    float* __restrict__ out,            // [C * windows_nb]
    int windows_nb)
{
    __shared__ __align__(16) float xs[4 * 2 * REG];        // 51200 B: 4 waves x 2 regions
    __shared__ __align__(16) __hip_bfloat16 wlds[C][72];   // 4608 B palette

    const int t    = threadIdx.x;
    const int lane = t & 63;
    const int lo   = lane & 15, hi = lane >> 4;
    const int wuni = __builtin_amdgcn_readfirstlane(t >> 6);
    const size_t b = blockIdx.x;

    // ---- weight palette, built once per block ----
    {
        const int c  = t >> 3;
        const int k0 = (t & 7) * 8;
        __hip_bfloat16 tmp[8];
#pragma unroll
        for (int e = 0; e < 8; ++e) {
            const int k = k0 + e;
            tmp[e] = __float2bfloat16(k < K ? weight[c * K + k] : 0.f);
        }
        *reinterpret_cast<bf16x8*>(&wlds[c][k0]) = *reinterpret_cast<bf16x8*>(tmp);
    }
    __syncthreads();                    // the only barrier in the kernel

    // ---- hoisted per-wave constants: B-fragments (weights) + bias ----
    bf16x8 bf_[2][2];                   // [n][ks]
#pragma unroll
    for (int n = 0; n < 2; ++n)
#pragma unroll
        for (int ks = 0; ks < 2; ++ks)
            bf_[n][ks] = *reinterpret_cast<const bf16x8*>(&wlds[n * 16 + lo][hi * 8 + ks * 32]);
    float bb[2];                        // acc channel = n*16+lo (same for all r)
#pragma unroll
    for (int n = 0; n < 2; ++n) bb[n] = bias[n * 16 + lo];

    float* __restrict__ P0 = xs + wuni * 2 * REG;
    float* __restrict__ P1 = P0 + REG;

    // wave's tile j covers windows  b*1024 + j*128 + wuni*32 .. +31
    auto gsrc = [&](int j) {
        return enc_x + (b * WPB + (size_t)j * 128 + (size_t)wuni * WPW) * (size_t)K;
    };
    auto stage = [&](const float* gw, float* r) {
#pragma unroll
        for (int q = 0; q < 6; ++q)
            __builtin_amdgcn_global_load_lds(GPTR(gw + q * 256 + lane * 4),
                                             LPTR(r + q * 256 + lane * 4), 16, 0, 0);
        __builtin_amdgcn_global_load_lds(GPTR(gw + 1536 + (lane < 32 ? lane : 31)),
                                         LPTR(r + 1536 + lane), 4, 0, 0);
    };

    // prologue: fill both regions
    stage(gsrc(0), P0);
    stage(gsrc(1), P1);

#pragma unroll
    for (int j = 0; j < NT; ++j) {
        float* __restrict__ Pc = (j & 1) ? P1 : P0;

        if (j == 0)          WAITV(7);       // younger: S1
        else if (j == NT-1)  WAITV(16);      // younger: st_{j-1}
        else                 WAITV(23);      // younger: st_{j-1} + S_{j+1}
        __builtin_amdgcn_sched_barrier(0);

        // A fragments: row = m*16+lo (window), k = hi*8 + ks*32 + e
        bf16x8 af[2][2];
#pragma unroll
        for (int m = 0; m < 2; ++m)
#pragma unroll
            for (int ks = 0; ks < 2; ++ks) {
                const int row = m * 16 + lo;
                short a8[8];
#pragma unroll
                for (int e = 0; e < 8; ++e) {
                    const int kk = hi * 8 + ks * 32 + e;
                    float v;
                    if (ks == 0) v = Pc[row * K + kk];
                    else         v = (hi * 8 + e < 17) ? Pc[row * K + kk] : 0.f;
                    a8[e] = f2bf(v);
                }
                af[m][ks] = *reinterpret_cast<bf16x8*>(a8);
            }

        // 8 MFMAs: 32 windows x 32 channels, bias pre-folded via C operand
        f32x4 acc[2][2];
#pragma unroll
        for (int m = 0; m < 2; ++m)
#pragma unroll
            for (int n = 0; n < 2; ++n)
                acc[m][n] = f32x4{bb[n], bb[n], bb[n], bb[n]};
#pragma unroll
        for (int ks = 0; ks < 2; ++ks)
#pragma unroll
            for (int m = 0; m < 2; ++m)
#pragma unroll
                for (int n = 0; n < 2; ++n)
                    acc[m][n] = __builtin_amdgcn_mfma_f32_16x16x32_bf16(
                        af[m][ks], bf_[n][ks], acc[m][n], 0, 0, 0);

        // epilogue: transpose via overlay of the (now dead) current region
        asm volatile("" ::: "memory");       // A ds_reads precede overlay writes
        float* __restrict__ cw = Pc;         // [32 ch][33]
#pragma unroll
        for (int m = 0; m < 2; ++m)
#pragma unroll
            for (int n = 0; n < 2; ++n)
#pragma unroll
                for (int r = 0; r < 4; ++r)
                    cw[(n * 16 + lo) * 33 + (m * 16 + hi * 4 + r)] = acc[m][n][r];

        // stores: 2 channel-planes x 32 windows per instr = 2 x 128B runs
        const size_t wt = b * WPB + (size_t)j * 128 + (size_t)wuni * WPW;
        const int win = lane & 31;
        const int ch  = lane >> 5;
#pragma unroll
        for (int ci = 0; ci < 16; ++ci) {
            const int c_ = 2 * ci + ch;
            out[(size_t)c_ * windows_nb + wt + win] = cw[c_ * 33 + win];
        }

        asm volatile("" ::: "memory");       // keep stores BEFORE next stage (FIFO counts)
        if (j + 2 < NT)
            stage(gsrc(j + 2), Pc);          // refill region just freed
    }
}

// R15 fallback (72.3 us) for windows_nb % 1024 != 0 but % 128 == 0.
__global__ __launch_bounds__(BLK) void conv2d_wavepipe(
    const float* __restrict__ enc_x, const float* __restrict__ weight,
    const float* __restrict__ bias, float* __restrict__ out, int windows_nb)
{
    __shared__ __align__(16) float xsw[4 * REG];
    __shared__ __align__(16) __hip_bfloat16 wlds[C][72];
    const int t = threadIdx.x, lane = t & 63, lo = lane & 15, hi = lane >> 4;
    const int wuni = __builtin_amdgcn_readfirstlane(t >> 6);
    const size_t b = blockIdx.x;
    {
        const int c = t >> 3, k0 = (t & 7) * 8;
        __hip_bfloat16 tmp[8];
#pragma unroll
        for (int e = 0; e < 8; ++e) {
            const int k = k0 + e;
            tmp[e] = __float2bfloat16(k < K ? weight[c * K + k] : 0.f);
        }
        *reinterpret_cast<bf16x8*>(&wlds[c][k0]) = *reinterpret_cast<bf16x8*>(tmp);
    }
    __syncthreads();
    float* __restrict__ xr = xsw + wuni * REG;
    const float* __restrict__ gw = enc_x + b * (size_t)(128 * K) + wuni * RF;
#pragma unroll
    for (int r = 0; r < 6; ++r)
        __builtin_amdgcn_global_load_lds(GPTR(gw + r * 256 + lane * 4),
                                         LPTR(xr + r * 256 + lane * 4), 16, 0, 0);
    __builtin_amdgcn_global_load_lds(GPTR(gw + 1536 + (lane < 32 ? lane : 31)),
                                     LPTR(xr + 1536 + lane), 4, 0, 0);
    WAITV(0);
    __builtin_amdgcn_sched_barrier(0);
    bf16x8 af[2][2];
#pragma unroll
    for (int m = 0; m < 2; ++m)
#pragma unroll
        for (int ks = 0; ks < 2; ++ks) {
            const int row = m * 16 + lo;
            short a8[8];
#pragma unroll
            for (int e = 0; e < 8; ++e) {
                const int kk = hi * 8 + ks * 32 + e;
                float v;
                if (ks == 0) v = xr[row * K + kk];
                else         v = (hi * 8 + e < 17) ? xr[row * K + kk] : 0.f;
                a8[e] = f2bf(v);
            }
            af[m][ks] = *reinterpret_cast<bf16x8*>(a8);
        }
    bf16x8 bf_[2][2];
#pragma unroll
    for (int n = 0; n < 2; ++n)
#pragma unroll
        for (int ks = 0; ks < 2; ++ks)
            bf_[n][ks] = *reinterpret_cast<const bf16x8*>(&wlds[n * 16 + lo][hi * 8 + ks * 32]);
    f32x4 acc[2][2];
#pragma unroll
    for (int m = 0; m < 2; ++m)
#pragma unroll
        for (int n = 0; n < 2; ++n) acc[m][n] = f32x4{0.f, 0.f, 0.f, 0.f};
#pragma unroll
    for (int ks = 0; ks < 2; ++ks)
#pragma unroll
        for (int m = 0; m < 2; ++m)
#pragma unroll
            for (int n = 0; n < 2; ++n)
                acc[m][n] = __builtin_amdgcn_mfma_f32_16x16x32_bf16(
                    af[m][ks], bf_[n][ks], acc[m][n], 0, 0, 0);
    asm volatile("" ::: "memory");
    float* __restrict__ cw = xr;
#pragma unroll
    for (int m = 0; m < 2; ++m)
#pragma unroll
        for (int n = 0; n < 2; ++n)
#pragma unroll
            for (int r = 0; r < 4; ++r)
                cw[(n * 16 + lo) * 33 + (m * 16 + hi * 4 + r)] = acc[m][n][r];
    const size_t wbase = b * (size_t)128 + wuni * WPW;
    const int win = lane & 31, ch = lane >> 5;
#pragma unroll
    for (int ci = 0; ci < 16; ++ci) {
        const int c_ = 2 * ci + ch;
        out[(size_t)c_ * windows_nb + wbase + win] = cw[c_ * 33 + win] + bias[c_];
    }
}

extern "C" void kernel_launch(void* const* d_in, const int* in_sizes, int n_in,
                              void* d_out, int out_size, void* d_ws, size_t ws_size,
                              hipStream_t stream) {
    const float* enc_x  = (const float*)d_in[0];
    const float* weight = (const float*)d_in[1];   // [C,7,7] flat
    const float* bias   = (const float*)d_in[2];   // [C]
    float* out = (float*)d_out;

    const int windows_nb = in_sizes[0] / K;        // 1048576 expected

    if ((windows_nb % WPB) == 0) {
        conv2d_pwave<<<windows_nb / WPB, BLK, 0, stream>>>(enc_x, weight, bias, out, windows_nb);
    } else {
        conv2d_wavepipe<<<windows_nb / 128, BLK, 0, stream>>>(enc_x, weight, bias, out, windows_nb);
    }
}

// Round 18
// 75.601 us; speedup vs baseline: 1.5195x; 1.1583x over previous
//
#include <hip/hip_runtime.h>
#include <hip/hip_bf16.h>
#include <stdint.h>

constexpr int K    = 49;             // 7x7 kernel flattened
constexpr int C    = 32;             // out channels
constexpr int WPW  = 32;             // windows per wave
constexpr int RF   = WPW * K;        // 1568 floats staged per wave
constexpr int REG  = 1600;           // region floats (tail slack)
constexpr int BLK  = 256;            // 4 fully independent waves
constexpr int TILE = 128;            // windows per block

typedef short bf16x8 __attribute__((ext_vector_type(8)));
typedef float f32x4  __attribute__((ext_vector_type(4)));
typedef float v4 __attribute__((ext_vector_type(4), aligned(4)));

#define GPTR(p) ((const __attribute__((address_space(1))) uint32_t*)(p))
#define LPTR(p) ((__attribute__((address_space(3))) uint32_t*)(p))
#define WAITV(n) asm volatile("s_waitcnt vmcnt(" #n ")" ::: "memory")

static __device__ __forceinline__ short f2bf(float f) {
    __hip_bfloat16 h = __float2bfloat16(f);      // RNE
    return __builtin_bit_cast(short, h);
}

// R15 core (72.3us champion) + palette-to-registers:
//  - B-fragments (weights) loaded global->reg per lane, one-time (~6 loads,
//    L2-resident weight). Deletes the 4.6KB LDS palette AND the kernel's only
//    __syncthreads -> zero barriers anywhere.
//  - LDS 25.6KB/block -> 6 blocks/CU = 24 independent wave-pipelines/CU
//    (R15: 5 blocks/20 waves; R17 regression = depth bought at occupancy cost).
__global__ __launch_bounds__(BLK) void conv2d_wavepipe2(
    const float* __restrict__ enc_x,
    const float* __restrict__ weight,   // [C*K]
    const float* __restrict__ bias,     // [C]
    float* __restrict__ out,            // [C * windows_nb]
    int windows_nb)
{
    __shared__ __align__(16) float xs[4 * REG];   // 25600 B, 4 private regions

    const int t    = threadIdx.x;
    const int lane = t & 63;
    const int lo   = lane & 15, hi = lane >> 4;
    const int wuni = __builtin_amdgcn_readfirstlane(t >> 6);
    const size_t b = blockIdx.x;

    // ---- stage own 32 rows FIRST (reads start immediately, no barrier) ----
    float* __restrict__ xr = xs + wuni * REG;
    const float* __restrict__ gw = enc_x + b * (size_t)(TILE * K) + wuni * RF;
#pragma unroll
    for (int r = 0; r < 6; ++r)
        __builtin_amdgcn_global_load_lds(GPTR(gw + r * 256 + lane * 4),
                                         LPTR(xr + r * 256 + lane * 4), 16, 0, 0);
    __builtin_amdgcn_global_load_lds(GPTR(gw + 1536 + (lane < 32 ? lane : 31)),
                                     LPTR(xr + 1536 + lane), 4, 0, 0);

    // ---- B-fragments (weights) global->reg while x-stage is in flight ----
    // lane's channel rows: lo and lo+16; k = hi*8 + ks*32 + e, k>=49 -> 0.
    bf16x8 bf_[2][2];                   // [n][ks]
#pragma unroll
    for (int n = 0; n < 2; ++n) {
        const float* __restrict__ wr = weight + (n * 16 + lo) * K;
        {   // ks = 0: k = hi*8 .. hi*8+7  (max 31 < 49, always valid)
            v4 a = *reinterpret_cast<const v4*>(wr + hi * 8);
            v4 c = *reinterpret_cast<const v4*>(wr + hi * 8 + 4);
            short s[8];
#pragma unroll
            for (int i = 0; i < 4; ++i) { s[i] = f2bf(a[i]); s[4 + i] = f2bf(c[i]); }
            bf_[n][0] = *reinterpret_cast<bf16x8*>(s);
        }
        {   // ks = 1: k = 32 + hi*8 + e; valid k <= 48
            short s[8] = {0, 0, 0, 0, 0, 0, 0, 0};
            if (hi < 2) {
                v4 a = *reinterpret_cast<const v4*>(wr + 32 + hi * 8);
                v4 c = *reinterpret_cast<const v4*>(wr + 36 + hi * 8);
#pragma unroll
                for (int i = 0; i < 4; ++i) { s[i] = f2bf(a[i]); s[4 + i] = f2bf(c[i]); }
            } else if (hi == 2) {
                s[0] = f2bf(wr[48]);
            }
            bf_[n][1] = *reinterpret_cast<bf16x8*>(s);
        }
    }
    // bias for acc channel n*16+lo (same for all r of the fragment)
    float bb[2];
#pragma unroll
    for (int n = 0; n < 2; ++n) bb[n] = bias[n * 16 + lo];

    WAITV(0);                           // own 7 stage ops (+wt loads) done
    __builtin_amdgcn_sched_barrier(0);

    // ---- A fragments: row = m*16+lo (window), k = hi*8 + ks*32 + e ----
    bf16x8 af[2][2];
#pragma unroll
    for (int m = 0; m < 2; ++m)
#pragma unroll
        for (int ks = 0; ks < 2; ++ks) {
            const int row = m * 16 + lo;
            short a8[8];
#pragma unroll
            for (int e = 0; e < 8; ++e) {
                const int kk = hi * 8 + ks * 32 + e;
                float v;
                if (ks == 0) v = xr[row * K + kk];                       // k <= 31
                else         v = (hi * 8 + e < 17) ? xr[row * K + kk] : 0.f;  // k <= 48
                a8[e] = f2bf(v);
            }
            af[m][ks] = *reinterpret_cast<bf16x8*>(a8);
        }

    // ---- 8 MFMAs: 32 windows x 32 channels, bias pre-folded in C ----
    f32x4 acc[2][2];
#pragma unroll
    for (int m = 0; m < 2; ++m)
#pragma unroll
        for (int n = 0; n < 2; ++n)
            acc[m][n] = f32x4{bb[n], bb[n], bb[n], bb[n]};
#pragma unroll
    for (int ks = 0; ks < 2; ++ks)
#pragma unroll
        for (int m = 0; m < 2; ++m)
#pragma unroll
            for (int n = 0; n < 2; ++n)
                acc[m][n] = __builtin_amdgcn_mfma_f32_16x16x32_bf16(
                    af[m][ks], bf_[n][ks], acc[m][n], 0, 0, 0);

    // ---- epilogue: transpose via overlay of own (dead) region ----
    asm volatile("" ::: "memory");      // A ds_reads precede overlay writes
    float* __restrict__ cw = xr;        // [32 ch][33] = 1056 <= REG
#pragma unroll
    for (int m = 0; m < 2; ++m)
#pragma unroll
        for (int n = 0; n < 2; ++n)
#pragma unroll
            for (int r = 0; r < 4; ++r)
                cw[(n * 16 + lo) * 33 + (m * 16 + hi * 4 + r)] = acc[m][n][r];

    // ---- stores: 2 channel-planes x 32 windows per instr (128B runs) ----
    const size_t wbase = b * (size_t)TILE + wuni * WPW;
    const int win = lane & 31;
    const int ch  = lane >> 5;
#pragma unroll
    for (int ci = 0; ci < 16; ++ci) {
        const int c_ = 2 * ci + ch;
        out[(size_t)c_ * windows_nb + wbase + win] = cw[c_ * 33 + win];
    }
}

// Known-good scalar fallback (R9 structure) for unexpected sizes.
__global__ __launch_bounds__(128, 8) void conv2d_split2u(
    const float* __restrict__ enc_x, const float* __restrict__ weight,
    const float* __restrict__ bias, float* __restrict__ out, int windows_nb)
{
    __shared__ __align__(16) float xsf[64 * K];
    const int t = threadIdx.x, lane = t & 63, wid = t >> 6;
    const size_t b = blockIdx.x;
    const float* __restrict__ g = enc_x + b * (size_t)(64 * K);
    if (wid == 0) {
#pragma unroll
        for (int r = 0; r < 6; ++r)
            __builtin_amdgcn_global_load_lds(GPTR(g + r * 256 + lane * 4),
                                             LPTR(xsf + r * 256 + lane * 4), 16, 0, 0);
    } else {
#pragma unroll
        for (int r = 6; r < 12; ++r)
            __builtin_amdgcn_global_load_lds(GPTR(g + r * 256 + lane * 4),
                                             LPTR(xsf + r * 256 + lane * 4), 16, 0, 0);
        __builtin_amdgcn_global_load_lds(GPTR(g + 3072 + lane),
                                         LPTR(xsf + 3072 + lane), 4, 0, 0);
    }
    asm volatile("s_waitcnt vmcnt(0)" ::: "memory");
    __builtin_amdgcn_s_barrier();
    const int c0 = __builtin_amdgcn_readfirstlane(wid) * 16;
    const float* __restrict__ wp = weight + c0 * K;
    float acc[16];
#pragma unroll
    for (int cc = 0; cc < 16; ++cc) acc[cc] = bias[c0 + cc];
    float x[25];
#pragma unroll
    for (int k = 0; k < 24; ++k) x[k] = xsf[lane * K + k];
#pragma unroll 2
    for (int cc = 0; cc < 16; ++cc) {
        const float* __restrict__ wc = wp + cc * K;
        float a = acc[cc];
#pragma unroll
        for (int k = 0; k < 24; ++k) a = fmaf(x[k], wc[k], a);
        acc[cc] = a;
    }
#pragma unroll
    for (int k = 0; k < 25; ++k) x[k] = xsf[lane * K + 24 + k];
#pragma unroll 2
    for (int cc = 0; cc < 16; ++cc) {
        const float* __restrict__ wc = wp + cc * K + 24;
        float a = acc[cc];
#pragma unroll
        for (int k = 0; k < 25; ++k) a = fmaf(x[k], wc[k], a);
        acc[cc] = a;
    }
    const size_t w = b * 64 + lane;
#pragma unroll
    for (int cc = 0; cc < 16; ++cc)
        out[(size_t)(c0 + cc) * windows_nb + w] = acc[cc];
}

extern "C" void kernel_launch(void* const* d_in, const int* in_sizes, int n_in,
                              void* d_out, int out_size, void* d_ws, size_t ws_size,
                              hipStream_t stream) {
    const float* enc_x  = (const float*)d_in[0];
    const float* weight = (const float*)d_in[1];   // [C,7,7] flat
    const float* bias   = (const float*)d_in[2];   // [C]
    float* out = (float*)d_out;

    const int windows_nb = in_sizes[0] / K;        // 1048576 expected

    if ((windows_nb % TILE) == 0) {
        conv2d_wavepipe2<<<windows_nb / TILE, BLK, 0, stream>>>(enc_x, weight, bias, out, windows_nb);
    } else {
        conv2d_split2u<<<(windows_nb + 63) / 64, 128, 0, stream>>>(enc_x, weight, bias, out, windows_nb);
    }
}

// Round 19
// 72.345 us; speedup vs baseline: 1.5879x; 1.0450x over previous
//
#include <hip/hip_runtime.h>
#include <hip/hip_bf16.h>
#include <stdint.h>

constexpr int K    = 49;             // 7x7 kernel flattened
constexpr int C    = 32;             // out channels
constexpr int TILE = 128;            // windows per block
constexpr int WPW  = 32;             // windows per wave
constexpr int RF   = WPW * K;        // 1568 floats staged per wave
constexpr int REG  = 1600;           // region floats (1568 + 32 tail slack)
constexpr int BLK  = 256;            // 4 waves

typedef short bf16x8 __attribute__((ext_vector_type(8)));
typedef float f32x4  __attribute__((ext_vector_type(4)));

#define GPTR(p) ((const __attribute__((address_space(1))) uint32_t*)(p))
#define LPTR(p) ((__attribute__((address_space(3))) uint32_t*)(p))
#define WAITV(n) asm volatile("s_waitcnt vmcnt(" #n ")" ::: "memory")

static __device__ __forceinline__ short f2bf(float f) {
    __hip_bfloat16 h = __float2bfloat16(f);      // RNE
    return __builtin_bit_cast(short, h);
}

// CHAMPION (R15, 72.3us): independent per-wave pipelines. Each wave stages
// ONLY its own 32 rows into a private LDS region and waits only on its own
// vmcnt; zero barriers on the x-path. LDS palette for weights (coalesced
// one-time build + broadcast ds_read -- R18 showed per-lane scattered weight
// loads are worse). 30.2KB/block -> 5 blocks/CU = 20 decorrelated waves/CU.
__global__ __launch_bounds__(BLK) void conv2d_wavepipe(
    const float* __restrict__ enc_x,
    const float* __restrict__ weight,   // [C*K]
    const float* __restrict__ bias,     // [C]
    float* __restrict__ out,            // [C * windows_nb]
    int windows_nb)
{
    __shared__ __align__(16) float xs[4 * REG];            // 25600 B, 4 private regions
    __shared__ __align__(16) __hip_bfloat16 wlds[C][72];   // 4608 B bf16 palette

    const int t    = threadIdx.x;
    const int lane = t & 63;
    const int lo   = lane & 15, hi = lane >> 4;
    const int wuni = __builtin_amdgcn_readfirstlane(t >> 6);  // SGPR wave id
    const size_t b = blockIdx.x;

    // ---- weight palette (R14-proven), before ANY x-VMEM is issued ----
    {
        const int c  = t >> 3;
        const int k0 = (t & 7) * 8;
        __hip_bfloat16 tmp[8];
#pragma unroll
        for (int e = 0; e < 8; ++e) {
            const int k = k0 + e;
            tmp[e] = __float2bfloat16(k < K ? weight[c * K + k] : 0.f);
        }
        *reinterpret_cast<bf16x8*>(&wlds[c][k0]) = *reinterpret_cast<bf16x8*>(tmp);
    }
    __syncthreads();     // orders only the tiny palette; x-stage not yet issued

    // ---------- per-wave independent from here on ----------
    float* __restrict__ xr = xs + wuni * REG;                       // private region
    const float* __restrict__ gw = enc_x + b * (size_t)(TILE * K) + wuni * RF;

    // stage own 6272 B: 6 x (64 lanes x 16 B) + clamped 4 B tail (lanes>=32
    // write dup junk into floats 1568..1599 slack -> never read as k<49 data)
#pragma unroll
    for (int r = 0; r < 6; ++r)
        __builtin_amdgcn_global_load_lds(GPTR(gw + r * 256 + lane * 4),
                                         LPTR(xr + r * 256 + lane * 4), 16, 0, 0);
    __builtin_amdgcn_global_load_lds(GPTR(gw + 1536 + (lane < 32 ? lane : 31)),
                                     LPTR(xr + 1536 + lane), 4, 0, 0);

    WAITV(0);                                  // waits OWN 7 ops only (no barrier)
    __builtin_amdgcn_sched_barrier(0);

    // ---- A fragments (M=own windows, K): row = m*16+lo, k = hi*8+ks*32+e ----
    bf16x8 af[2][2];                           // [m][ks]
#pragma unroll
    for (int m = 0; m < 2; ++m)
#pragma unroll
        for (int ks = 0; ks < 2; ++ks) {
            const int row = m * 16 + lo;
            short a8[8];
#pragma unroll
            for (int e = 0; e < 8; ++e) {
                const int kk = hi * 8 + ks * 32 + e;
                float v;
                if (ks == 0) v = xr[row * K + kk];                    // k<=31 valid
                else         v = (hi * 8 + e < 17) ? xr[row * K + kk] : 0.f;  // k<49
                a8[e] = f2bf(v);
            }
            af[m][ks] = *reinterpret_cast<bf16x8*>(a8);
        }

    // ---- B fragments from palette: 16B-aligned ds_read_b128 ----
    bf16x8 bf_[2][2];                          // [n][ks]
#pragma unroll
    for (int n = 0; n < 2; ++n)
#pragma unroll
        for (int ks = 0; ks < 2; ++ks)
            bf_[n][ks] = *reinterpret_cast<const bf16x8*>(&wlds[n * 16 + lo][hi * 8 + ks * 32]);

    // ---- 8 MFMAs: 32 windows x 32 channels per wave ----
    f32x4 acc[2][2];
#pragma unroll
    for (int m = 0; m < 2; ++m)
#pragma unroll
        for (int n = 0; n < 2; ++n) acc[m][n] = f32x4{0.f, 0.f, 0.f, 0.f};
#pragma unroll
    for (int ks = 0; ks < 2; ++ks)
#pragma unroll
        for (int m = 0; m < 2; ++m)
#pragma unroll
            for (int n = 0; n < 2; ++n)
                acc[m][n] = __builtin_amdgcn_mfma_f32_16x16x32_bf16(
                    af[m][ks], bf_[n][ks], acc[m][n], 0, 0, 0);

    // ---- epilogue: transpose via private cs overlay of own (dead) region ----
    asm volatile("" ::: "memory");             // keep A ds_reads before overlay writes
    float* __restrict__ cw = xr;               // [32 c][33] = 1056 floats <= REG
#pragma unroll
    for (int m = 0; m < 2; ++m)
#pragma unroll
        for (int n = 0; n < 2; ++n)
#pragma unroll
            for (int r = 0; r < 4; ++r)
                cw[(n * 16 + lo) * 33 + (m * 16 + hi * 4 + r)] = acc[m][n][r];

    // ---- stores: 2 channels x 32 windows per instr, 16 instrs, no barrier ----
    const size_t wbase = b * (size_t)TILE + wuni * WPW;
    const int win = lane & 31;
    const int ch  = lane >> 5;                 // 0/1
#pragma unroll
    for (int ci = 0; ci < 16; ++ci) {
        const int c_ = 2 * ci + ch;
        out[(size_t)c_ * windows_nb + wbase + win] = cw[c_ * 33 + win] + bias[c_];
    }
}

// Known-good fallback (R9, 79.5 us) for unexpected sizes.
__global__ __launch_bounds__(128, 8) void conv2d_split2u(
    const float* __restrict__ enc_x, const float* __restrict__ weight,
    const float* __restrict__ bias, float* __restrict__ out, int windows_nb)
{
    __shared__ __align__(16) float xsf[64 * K];
    const int t = threadIdx.x, lane = t & 63, wid = t >> 6;
    const size_t b = blockIdx.x;
    const float* __restrict__ g = enc_x + b * (size_t)(64 * K);
    if (wid == 0) {
#pragma unroll
        for (int r = 0; r < 6; ++r)
            __builtin_amdgcn_global_load_lds(GPTR(g + r * 256 + lane * 4),
                                             LPTR(xsf + r * 256 + lane * 4), 16, 0, 0);
    } else {
#pragma unroll
        for (int r = 6; r < 12; ++r)
            __builtin_amdgcn_global_load_lds(GPTR(g + r * 256 + lane * 4),
                                             LPTR(xsf + r * 256 + lane * 4), 16, 0, 0);
        __builtin_amdgcn_global_load_lds(GPTR(g + 3072 + lane),
                                         LPTR(xsf + 3072 + lane), 4, 0, 0);
    }
    asm volatile("s_waitcnt vmcnt(0)" ::: "memory");
    __builtin_amdgcn_s_barrier();
    const int c0 = __builtin_amdgcn_readfirstlane(wid) * 16;
    const float* __restrict__ wp = weight + c0 * K;
    float acc[16];
#pragma unroll
    for (int cc = 0; cc < 16; ++cc) acc[cc] = bias[c0 + cc];
    float x[25];
#pragma unroll
    for (int k = 0; k < 24; ++k) x[k] = xsf[lane * K + k];
#pragma unroll 2
    for (int cc = 0; cc < 16; ++cc) {
        const float* __restrict__ wc = wp + cc * K;
        float a = acc[cc];
#pragma unroll
        for (int k = 0; k < 24; ++k) a = fmaf(x[k], wc[k], a);
        acc[cc] = a;
    }
#pragma unroll
    for (int k = 0; k < 25; ++k) x[k] = xsf[lane * K + 24 + k];
#pragma unroll 2
    for (int cc = 0; cc < 16; ++cc) {
        const float* __restrict__ wc = wp + cc * K + 24;
        float a = acc[cc];
#pragma unroll
        for (int k = 0; k < 25; ++k) a = fmaf(x[k], wc[k], a);
        acc[cc] = a;
    }
    const size_t w = b * 64 + lane;
#pragma unroll
    for (int cc = 0; cc < 16; ++cc)
        out[(size_t)(c0 + cc) * windows_nb + w] = acc[cc];
}

extern "C" void kernel_launch(void* const* d_in, const int* in_sizes, int n_in,
                              void* d_out, int out_size, void* d_ws, size_t ws_size,
                              hipStream_t stream) {
    const float* enc_x  = (const float*)d_in[0];
    const float* weight = (const float*)d_in[1];   // [C,7,7] flat
    const float* bias   = (const float*)d_in[2];   // [C]
    float* out = (float*)d_out;

    const int windows_nb = in_sizes[0] / K;        // 1048576 expected

    if ((windows_nb % TILE) == 0) {
        conv2d_wavepipe<<<windows_nb / TILE, BLK, 0, stream>>>(enc_x, weight, bias, out, windows_nb);
    } else {
        conv2d_split2u<<<(windows_nb + 63) / 64, 128, 0, stream>>>(enc_x, weight, bias, out, windows_nb);
    }
}